// Round 23
// baseline (246.910 us; speedup 1.0000x reference)
//
#include <hip/hip_runtime.h>
#include <hip/hip_bf16.h>

#define TKN   2048
#define CDIM  256
#define PDIM  32
#define ODIM  32
#define HIDD  128
#define CCSZ  65536
#define TOTSZ 66560
#define KSPL  16

typedef unsigned short u16;
typedef __bf16 bf16x8 __attribute__((ext_vector_type(8)));
typedef float f32x4 __attribute__((ext_vector_type(4)));
typedef unsigned short u16x4 __attribute__((ext_vector_type(4)));
typedef unsigned short u16x8 __attribute__((ext_vector_type(8)));

__device__ __forceinline__ u16 f2b(float f){
  __hip_bfloat16 h = __float2bfloat16(f);
  return *reinterpret_cast<u16*>(&h);
}
__device__ __forceinline__ float gelu_fast(float x){
  const float z = 1.5957691216057308f * (x + 0.044715f * x * x * x);
  return x / (1.0f + __expf(-z));
}
// async global->LDS, 16B per lane; LDS dest = wave-uniform base + lane*16 (linear).
__device__ __forceinline__ void gload16(const void* g, void* l){
  __builtin_amdgcn_global_load_lds(
      (const __attribute__((address_space(1))) unsigned int*)g,
      (__attribute__((address_space(3))) unsigned int*)l, 16, 0, 0);
}

// ---------------- prep: layernorm + h = q@w1.T + b1  -> H bf16 [2048][128]
__global__ __launch_bounds__(256) void k_prep_h(
    const float* __restrict__ query, const float* __restrict__ ln_w,
    const float* __restrict__ ln_b, const float* __restrict__ w1,
    const float* __restrict__ b1, u16* __restrict__ H){
  const int t = blockIdx.x;
  const int tid = threadIdx.x;
  __shared__ float qs[CDIM];
  __shared__ float red[8];
  __shared__ float stat[2];
  float v = query[(size_t)t*CDIM + tid];
  float s = v, s2 = v*v;
  #pragma unroll
  for(int o=32;o>0;o>>=1){ s += __shfl_down(s,o,64); s2 += __shfl_down(s2,o,64); }
  const int wv = tid>>6;
  if((tid&63)==0){ red[wv]=s; red[4+wv]=s2; }
  __syncthreads();
  if(tid==0){
    float ss=red[0]+red[1]+red[2]+red[3];
    float qq=red[4]+red[5]+red[6]+red[7];
    float mu=ss/(float)CDIM;
    float var=qq/(float)CDIM - mu*mu;
    stat[0]=mu; stat[1]=rsqrtf(var+1e-6f);
  }
  __syncthreads();
  qs[tid] = (v - stat[0])*stat[1]*ln_w[tid] + ln_b[tid];
  __syncthreads();
  if(tid < HIDD){
    const float* wr = w1 + (size_t)tid*CDIM;
    float acc = b1[tid];
    #pragma unroll 8
    for(int c=0;c<CDIM;c++) acc += qs[c]*wr[c];
    H[(size_t)t*HIDD + tid] = f2b(acc);
  }
}

// ---------------- prep: w2 -> bf16 in FRAGMENT-BLOCKED layout (r13-verified).
__global__ __launch_bounds__(256) void k_prep_w2(
    const float* __restrict__ w2, const float* __restrict__ b2,
    u16* __restrict__ w2s, float* __restrict__ b2p){
  const int gid = blockIdx.x*256 + threadIdx.x;   // 66560*16 threads
  const int n  = gid >> 4;
  const int ch = gid & 15;
  if(n >= TOTSZ) return;
  int j;
  if(n < CCSZ){
    const int f = n >> 9, rem = n & 511;
    const int g = rem >> 7, r = (rem >> 3) & 15, e = rem & 7;
    const int d = (f >> 3)*16 + r;
    const int c = (f & 7)*32 + g*8 + e;
    j = c*256 + d;
  } else {
    j = n;
  }
  const float* src = w2 + (size_t)j*HIDD + ch*8;
  u16x8 tv;
  #pragma unroll
  for(int i=0;i<8;i++) tv[i] = f2b(src[i]);
  const int q = n >> 7, ks = ch >> 2, nt8 = (n >> 4) & 7, kg = ch & 3, r15 = n & 15;
  *(u16x8*)(w2s + ((size_t)((q*4 + ks)*8 + nt8))*512 + (kg*16 + r15)*8) = tv;
  if(ch == 0) b2p[n] = b2[j];
}

// ---------------- prep: proj_w -> bf16 in k'-PERMUTED order (r17-verified).
__global__ __launch_bounds__(256) void k_prep_pw(
    const float* __restrict__ pw, u16* __restrict__ pwb){
  const int gid = blockIdx.x*256 + threadIdx.x;   // 524288 u16x4 chunks (2048 blocks)
  const int e = gid >> 11;
  const int kp = (gid & 2047)*4;
  const int grp = kp >> 8;
  const int rem = kp & 255;
  const int g = rem >> 6, r15 = (rem >> 2) & 15;
  const int w_ = grp >> 2, mt = (grp >> 1) & 1, nt = grp & 1;
  const int o = nt*16 + r15;
  const int d0 = w_*32 + mt*16 + g*4;
  const float* s = pw + (size_t)e*8192 + o*256 + d0;
  u16x4 tv;
  tv[0]=f2b(s[0]); tv[1]=f2b(s[1]); tv[2]=f2b(s[2]); tv[3]=f2b(s[3]);
  *(u16x4*)(pwb + (size_t)e*8192 + kp) = tv;
}

// ---------------- params GEMM v9.3 standalone (r20/r22 proven; f-major pbuf)
__global__ __launch_bounds__(256, 3) void k_params(
    const u16* __restrict__ H, const u16* __restrict__ w2s,
    const float* __restrict__ b2p, u16* __restrict__ pbuf, int chnk){
  __shared__ __align__(16) u16 S[4][16][136];
  const int tid = threadIdx.x;
  const int lane = tid & 63;
  const int w = tid >> 6;
  const int q = blockIdx.x;
  const int n0 = q * 128;
  const int r15 = lane & 15, g = lane >> 4;
  const int tb = blockIdx.y*128 + w*16;
  bf16x8 afr[2][4];
  #pragma unroll
  for(int m=0;m<2;m++){
    const u16* ap = H + (size_t)(tb + m*64 + r15)*HIDD + g*8;
    #pragma unroll
    for(int ks=0;ks<4;ks++) afr[m][ks] = *(const bf16x8*)(ap + ks*32);
  }
  float b2v[8];
  #pragma unroll
  for(int nt=0;nt<8;nt++) b2v[nt] = b2p[n0 + nt*16 + r15];
  f32x4 acc[2][8] = {};
  #pragma unroll
  for(int ks=0;ks<4;ks++){
    bf16x8 bfr[8];
    #pragma unroll
    for(int nt=0;nt<8;nt++)
      bfr[nt] = *(const bf16x8*)(w2s + ((size_t)((q*4 + ks)*8 + nt))*512 + lane*8);
    #pragma unroll
    for(int m=0;m<2;m++)
      #pragma unroll
      for(int nt=0;nt<8;nt++)
        acc[m][nt] = __builtin_amdgcn_mfma_f32_16x16x32_bf16(afr[m][ks], bfr[nt], acc[m][nt], 0,0,0);
  }
  #pragma unroll
  for(int m=0;m<2;m++){
    #pragma unroll
    for(int nt=0;nt<8;nt++)
      #pragma unroll
      for(int r=0;r<4;r++)
        S[w][g*4 + r][nt*16 + r15] = f2b(acc[m][nt][r] + b2v[nt]);
    u16* dst = pbuf + ((size_t)(q>>2)*chnk + tb + m*64)*512 + (q&3)*128;
    #pragma unroll
    for(int i=0;i<4;i++){
      const int lt = i*4 + (lane >> 4);
      const int jc = lane & 15;
      *(u16x8*)(dst + (size_t)lt*512 + jc*8) = *(const u16x8*)&S[w][lt][jc*8];
    }
  }
}

// ---------------- per-token chain v9 standalone (r22 proven)
__global__ __launch_bounds__(512, 2) void k_token(
    const float* __restrict__ xg, const u16* __restrict__ pbuf,
    const float* __restrict__ m_beta, const float* __restrict__ s_beta,
    u16* __restrict__ out2, int chnk){
  __shared__ u16 xs[PDIM][264];
  __shared__ u16 o1[CDIM][36];
  const int tl = blockIdx.x;
  const int tid = threadIdx.x;
  const int lane = tid & 63;
  const int w = tid >> 6;
  const int r15 = lane & 15, g = lane >> 4;

  bf16x8 af[2][8];
  #pragma unroll
  for(int ks=0;ks<8;ks++)
    #pragma unroll
    for(int mt=0;mt<2;mt++){
      const int f = (w*2+mt)*8 + ks;
      af[mt][ks] = *(const bf16x8*)(pbuf + ((size_t)f*chnk + tl)*512 + lane*8);
    }
  {
    const f32x4* src = (const f32x4*)(xg + (size_t)tl*8192);
    #pragma unroll
    for(int i=0;i<4;i++){
      const int idx = tid + 512*i;
      f32x4 v = src[idx];
      const int flat = idx*4;
      const int p = flat >> 8, c = flat & 255;
      u16x4 t4; t4[0]=f2b(v[0]); t4[1]=f2b(v[1]); t4[2]=f2b(v[2]); t4[3]=f2b(v[3]);
      *(u16x4*)&xs[p][c] = t4;
    }
  }
  __syncthreads();

  f32x4 acc[2][2] = {};
  #pragma unroll
  for(int ks=0;ks<8;ks++){
    bf16x8 bf[2];
    #pragma unroll
    for(int nt=0;nt<2;nt++){
      const int p = nt*16 + r15;
      bf[nt] = *(const bf16x8*)&xs[p][ks*32 + g*8];
    }
    #pragma unroll
    for(int mt=0;mt<2;mt++)
      #pragma unroll
      for(int nt=0;nt<2;nt++)
        acc[mt][nt] = __builtin_amdgcn_mfma_f32_16x16x32_bf16(af[mt][ks], bf[nt], acc[mt][nt], 0,0,0);
  }
  bf16x8 bf2[2];
  #pragma unroll
  for(int nt=0;nt<2;nt++){
    const int o = nt*16 + r15;
    const int flat = o*32 + g*8;
    bf2[nt] = *(const bf16x8*)(pbuf + ((size_t)(128 + (flat>>9))*chnk + tl)*512 + (flat & 511));
  }
  #pragma unroll
  for(int mt=0;mt<2;mt++){
    const int d0 = w*32 + mt*16 + g*4;
    const f32x4 mb = *(const f32x4*)&m_beta[d0];
    #pragma unroll
    for(int nt=0;nt<2;nt++){
      const int p = nt*16 + r15;
      #pragma unroll
      for(int r=0;r<4;r++)
        o1[d0+r][p] = f2b(gelu_fast(acc[mt][nt][r] + mb[r]));
    }
  }
  f32x4 acc2[2][2] = {};
  {
    bf16x8 af2[2];
    #pragma unroll
    for(int mt=0;mt<2;mt++){
      const int d = w*32 + mt*16 + r15;
      af2[mt] = *(const bf16x8*)&o1[d][g*8];
    }
    #pragma unroll
    for(int mt=0;mt<2;mt++)
      #pragma unroll
      for(int nt=0;nt<2;nt++)
        acc2[mt][nt] = __builtin_amdgcn_mfma_f32_16x16x32_bf16(af2[mt], bf2[nt], acc2[mt][nt], 0,0,0);
  }
  u16* dst = out2 + (size_t)tl*8192 + w*1024;
  #pragma unroll
  for(int nt=0;nt<2;nt++){
    const float sb = s_beta[nt*16 + r15];
    #pragma unroll
    for(int mt=0;mt<2;mt++){
      u16x4 t4;
      #pragma unroll
      for(int r=0;r<4;r++) t4[r] = f2b(gelu_fast(acc2[mt][nt][r] + sb));
      *(u16x4*)(dst + (mt*2+nt)*256 + lane*4) = t4;
    }
  }
}

// ---------------- FUSED: params(ch i, -> pbufW) blocks + token(ch i-1, <- pbufR)
// blocks co-scheduled in ONE launch. Complementary stalls (params: store-bound;
// token: load-latency) fill each other (m114 co-scheduling). Double-buffered pbuf
// removes the RAW race. Params role: 8 waves = 2 m-steps x 128 tokens, same v9.3
// math + f-major layout. Token role: r22 v9 verbatim. LDS union 35328B.
__global__ __launch_bounds__(512, 2) void k_fused(
    const float* __restrict__ xg, const u16* __restrict__ pbufR,
    u16* __restrict__ pbufW, const u16* __restrict__ H,
    const u16* __restrict__ w2s, const float* __restrict__ b2p,
    const float* __restrict__ m_beta, const float* __restrict__ s_beta,
    u16* __restrict__ out2, int chnk, int nP){
  __shared__ __align__(16) char ldsraw[35328];
  const int bid = blockIdx.x;
  const int tid = threadIdx.x;
  const int lane = tid & 63;
  const int w = tid >> 6;
  const int r15 = lane & 15, g = lane >> 4;

  if(bid < nP){
    // ---- params role ----
    u16 (*S)[16][136] = (u16 (*)[16][136])ldsraw;   // [8][16][136] = 34816B
    const int nYP = nP / 520;          // chnk/256
    const int q  = bid / nYP;
    const int y  = bid - q*nYP;
    const int n0 = q * 128;
    const int tb = y*256 + w*16;       // 8 waves cover 128; m adds 128
    bf16x8 afr[2][4];
    #pragma unroll
    for(int m=0;m<2;m++){
      const u16* ap = H + (size_t)(tb + m*128 + r15)*HIDD + g*8;
      #pragma unroll
      for(int ks=0;ks<4;ks++) afr[m][ks] = *(const bf16x8*)(ap + ks*32);
    }
    float b2v[8];
    #pragma unroll
    for(int nt=0;nt<8;nt++) b2v[nt] = b2p[n0 + nt*16 + r15];
    f32x4 acc[2][8] = {};
    #pragma unroll
    for(int ks=0;ks<4;ks++){
      bf16x8 bfr[8];
      #pragma unroll
      for(int nt=0;nt<8;nt++)
        bfr[nt] = *(const bf16x8*)(w2s + ((size_t)((q*4 + ks)*8 + nt))*512 + lane*8);
      #pragma unroll
      for(int m=0;m<2;m++)
        #pragma unroll
        for(int nt=0;nt<8;nt++)
          acc[m][nt] = __builtin_amdgcn_mfma_f32_16x16x32_bf16(afr[m][ks], bfr[nt], acc[m][nt], 0,0,0);
    }
    #pragma unroll
    for(int m=0;m<2;m++){
      #pragma unroll
      for(int nt=0;nt<8;nt++)
        #pragma unroll
        for(int r=0;r<4;r++)
          S[w][g*4 + r][nt*16 + r15] = f2b(acc[m][nt][r] + b2v[nt]);
      const int t0 = tb + m*128;
      u16* dst = pbufW + ((size_t)(q>>2)*chnk + t0)*512 + (q&3)*128;
      #pragma unroll
      for(int i=0;i<4;i++){
        const int lt = i*4 + (lane >> 4);
        const int jc = lane & 15;
        *(u16x8*)(dst + (size_t)lt*512 + jc*8) = *(const u16x8*)&S[w][lt][jc*8];
      }
    }
  } else {
    // ---- token role (r22 v9) ----
    u16 (*xs)[264] = (u16 (*)[264])ldsraw;                  // 16896B
    u16 (*o1)[36]  = (u16 (*)[36])(ldsraw + 16896);         // 18432B
    const int tl = bid - nP;
    bf16x8 af[2][8];
    #pragma unroll
    for(int ks=0;ks<8;ks++)
      #pragma unroll
      for(int mt=0;mt<2;mt++){
        const int f = (w*2+mt)*8 + ks;
        af[mt][ks] = *(const bf16x8*)(pbufR + ((size_t)f*chnk + tl)*512 + lane*8);
      }
    {
      const f32x4* src = (const f32x4*)(xg + (size_t)tl*8192);
      #pragma unroll
      for(int i=0;i<4;i++){
        const int idx = tid + 512*i;
        f32x4 v = src[idx];
        const int flat = idx*4;
        const int p = flat >> 8, c = flat & 255;
        u16x4 t4; t4[0]=f2b(v[0]); t4[1]=f2b(v[1]); t4[2]=f2b(v[2]); t4[3]=f2b(v[3]);
        *(u16x4*)&xs[p][c] = t4;
      }
    }
    __syncthreads();
    f32x4 acc[2][2] = {};
    #pragma unroll
    for(int ks=0;ks<8;ks++){
      bf16x8 bf[2];
      #pragma unroll
      for(int nt=0;nt<2;nt++){
        const int p = nt*16 + r15;
        bf[nt] = *(const bf16x8*)&xs[p][ks*32 + g*8];
      }
      #pragma unroll
      for(int mt=0;mt<2;mt++)
        #pragma unroll
        for(int nt=0;nt<2;nt++)
          acc[mt][nt] = __builtin_amdgcn_mfma_f32_16x16x32_bf16(af[mt][ks], bf[nt], acc[mt][nt], 0,0,0);
    }
    bf16x8 bf2[2];
    #pragma unroll
    for(int nt=0;nt<2;nt++){
      const int o = nt*16 + r15;
      const int flat = o*32 + g*8;
      bf2[nt] = *(const bf16x8*)(pbufR + ((size_t)(128 + (flat>>9))*chnk + tl)*512 + (flat & 511));
    }
    #pragma unroll
    for(int mt=0;mt<2;mt++){
      const int d0 = w*32 + mt*16 + g*4;
      const f32x4 mb = *(const f32x4*)&m_beta[d0];
      #pragma unroll
      for(int nt=0;nt<2;nt++){
        const int p = nt*16 + r15;
        #pragma unroll
        for(int r=0;r<4;r++)
          o1[d0+r][p] = f2b(gelu_fast(acc[mt][nt][r] + mb[r]));
      }
    }
    f32x4 acc2[2][2] = {};
    {
      bf16x8 af2[2];
      #pragma unroll
      for(int mt=0;mt<2;mt++){
        const int d = w*32 + mt*16 + r15;
        af2[mt] = *(const bf16x8*)&o1[d][g*8];
      }
      #pragma unroll
      for(int mt=0;mt<2;mt++)
        #pragma unroll
        for(int nt=0;nt<2;nt++)
          acc2[mt][nt] = __builtin_amdgcn_mfma_f32_16x16x32_bf16(af2[mt], bf2[nt], acc2[mt][nt], 0,0,0);
    }
    u16* dst = out2 + (size_t)tl*8192 + w*1024;
    #pragma unroll
    for(int nt=0;nt<2;nt++){
      const float sb = s_beta[nt*16 + r15];
      #pragma unroll
      for(int mt=0;mt<2;mt++){
        u16x4 t4;
        #pragma unroll
        for(int r=0;r<4;r++) t4[r] = f2b(gelu_fast(acc2[mt][nt][r] + sb));
        *(u16x4*)(dst + (mt*2+nt)*256 + lane*4) = t4;
      }
    }
  }
}

// ---------------- proj GEMM: 2-phase LDS-pipelined (k'-space; r17-verified).
__global__ __launch_bounds__(512) void k_proj(
    const u16* __restrict__ out2, const u16* __restrict__ pwb,
    float* __restrict__ part){
  __shared__ u16 Ab[2][64*32];
  __shared__ u16 Bb[2][256*32];
  const int tid = threadIdx.x;
  const int lane = tid & 63, w = tid >> 6;
  const int r15 = lane & 15, g = lane >> 4;
  const int m0 = blockIdx.x * 64;
  const int k0 = blockIdx.y * 512;
  const int wm = (w >> 2) * 32;
  const int wn = (w & 3) * 64;
  const int srow = lane >> 2;
  const int cs   = lane & 3;
  const int a_row = (w & 3)*16 + srow;
  const u16* a_src = out2 + (size_t)(m0 + a_row)*8192 + k0 + (size_t)((cs ^ (a_row & 3))*8);
  const int b_row0 = (2*w)*16 + srow;
  const int b_row1 = (2*w+1)*16 + srow;
  const u16* b_src0 = pwb + (size_t)b_row0*8192 + k0 + (size_t)((cs ^ (b_row0 & 3))*8);
  const u16* b_src1 = pwb + (size_t)b_row1*8192 + k0 + (size_t)((cs ^ (b_row1 & 3))*8);

  f32x4 acc[2][4] = {};

  #define STAGE(buf, kt) do{                                         \
    const int ko = (kt)*32;                                          \
    if(w < 4) gload16(a_src + ko, (char*)&Ab[buf][0] + w*1024);      \
    gload16(b_src0 + ko, (char*)&Bb[buf][0] + (2*w)*1024);           \
    gload16(b_src1 + ko, (char*)&Bb[buf][0] + (2*w+1)*1024);         \
  }while(0)

  STAGE(0, 0);
  __syncthreads();
  int cur = 0;
  for(int kt=0; kt<16; kt++){
    if(kt < 15){ STAGE(cur^1, kt+1); }
    bf16x8 af[2], bf[4];
    #pragma unroll
    for(int mt=0;mt<2;mt++){
      const int row = wm + mt*16 + r15;
      af[mt] = *(const bf16x8*)((char*)&Ab[cur][0] + row*64 + ((g ^ (row&3))*16));
    }
    #pragma unroll
    for(int nt=0;nt<4;nt++){
      const int row = wn + nt*16 + r15;
      bf[nt] = *(const bf16x8*)((char*)&Bb[cur][0] + row*64 + ((g ^ (row&3))*16));
    }
    #pragma unroll
    for(int mt=0;mt<2;mt++)
      #pragma unroll
      for(int nt=0;nt<4;nt++)
        acc[mt][nt] = __builtin_amdgcn_mfma_f32_16x16x32_bf16(af[mt], bf[nt], acc[mt][nt], 0,0,0);
    __syncthreads();
    cur ^= 1;
  }
  #undef STAGE

  float* pbase = part + (size_t)blockIdx.y*TKN*CDIM;
  #pragma unroll
  for(int mt=0;mt<2;mt++)
    #pragma unroll
    for(int nt=0;nt<4;nt++){
      const int t = m0 + wm + mt*16 + g*4;
      const int e = wn + nt*16 + r15;
      #pragma unroll
      for(int r=0;r<4;r++)
        pbase[(size_t)(t+r)*CDIM + e] = acc[mt][nt][r];
    }
}

// ---------------- combine partials + proj_b (f32x4 vectorized; 512 blocks)
__global__ __launch_bounds__(256) void k_combine(
    const float* __restrict__ part, const float* __restrict__ pb,
    float* __restrict__ out){
  const int i4 = blockIdx.x*256 + threadIdx.x;   // 131072 f32x4's
  const int e4 = (i4 & 63)*4;
  f32x4 s = *(const f32x4*)&pb[e4];
  #pragma unroll
  for(int z=0;z<KSPL;z++) s += *(const f32x4*)&part[(size_t)z*524288 + (size_t)i4*4];
  *(f32x4*)&out[(size_t)i4*4] = s;
}

extern "C" void kernel_launch(void* const* d_in, const int* in_sizes, int n_in,
                              void* d_out, int out_size, void* d_ws, size_t ws_size,
                              hipStream_t stream){
  const float* x     = (const float*)d_in[0];
  const float* query = (const float*)d_in[1];
  const float* ln_w  = (const float*)d_in[2];
  const float* ln_b  = (const float*)d_in[3];
  const float* w1    = (const float*)d_in[4];
  const float* b1    = (const float*)d_in[5];
  const float* w2    = (const float*)d_in[6];
  const float* b2    = (const float*)d_in[7];
  const float* m_beta= (const float*)d_in[8];
  const float* s_beta= (const float*)d_in[9];
  const float* pw    = (const float*)d_in[10];
  const float* pb    = (const float*)d_in[11];
  float* out = (float*)d_out;
  char* ws = (char*)d_ws;

  // Pipelined path: chnk=512 with DOUBLE-BUFFERED pbuf (2 x 68 MB); needs ~192 MB
  // (measured ws = 256 MiB). Fallback: chnk=256 (2 x 34 MB, ~124 MB total).
  const int chnk = (ws_size >= 200u*1024u*1024u) ? 512 : 256;
  const int nch  = TKN / chnk;
  const int nP   = 520 * (chnk/256);   // fused-kernel params-role blocks

  size_t off = 0;
  u16* H     = (u16*)(ws + off);  off += (size_t)TKN*HIDD*2;
  u16* w2s   = (u16*)(ws + off);  off += (size_t)TOTSZ*HIDD*2;
  float* b2p = (float*)(ws + off);off += (size_t)TOTSZ*4;
  u16* pwb   = (u16*)(ws + off);  off += (size_t)CDIM*8192*2;
  u16* pbuf0 = (u16*)(ws + off);  off += (size_t)chnk*TOTSZ*2;
  u16* pbuf1 = (u16*)(ws + off);  off += (size_t)chnk*TOTSZ*2;
  u16* out2  = (u16*)(ws + off);  off += (size_t)TKN*8192*2;
  // part (33.55 MB) aliases pbuf0 (>=34 MB, dead by k_proj).
  float* part= (float*)pbuf0;
  u16* pbufs[2] = {pbuf0, pbuf1};

  k_prep_h<<<TKN, 256, 0, stream>>>(query, ln_w, ln_b, w1, b1, H);
  k_prep_w2<<<4160, 256, 0, stream>>>(w2, b2, w2s, b2p);
  k_prep_pw<<<2048, 256, 0, stream>>>(pw, pwb);

  // software pipeline: params(0) | fused(params i, token i-1) | token(nch-1)
  k_params<<<dim3(520, chnk/128), 256, 0, stream>>>(H, w2s, b2p, pbufs[0], chnk);
  for(int i=1; i<nch; i++){
    k_fused<<<nP + chnk, 512, 0, stream>>>(
        x + (size_t)(i-1)*chnk*8192, pbufs[(i-1)&1], pbufs[i&1],
        H + (size_t)i*chnk*HIDD, w2s, b2p, m_beta, s_beta,
        out2 + (size_t)(i-1)*chnk*8192, chnk, nP);
  }
  k_token<<<chnk, 512, 0, stream>>>(x + (size_t)(nch-1)*chnk*8192, pbufs[(nch-1)&1],
                                    m_beta, s_beta,
                                    out2 + (size_t)(nch-1)*chnk*8192, chnk);

  k_proj<<<dim3(32,KSPL), 512, 0, stream>>>(out2, pwb, part);
  k_combine<<<512, 256, 0, stream>>>(part, pb, out);
}

// Round 24
// 219.696 us; speedup vs baseline: 1.1239x; 1.1239x over previous
//
#include <hip/hip_runtime.h>
#include <hip/hip_bf16.h>

#define TKN   2048
#define CDIM  256
#define PDIM  32
#define ODIM  32
#define HIDD  128
#define CCSZ  65536
#define TOTSZ 66560
#define KSPL  16

typedef unsigned short u16;
typedef __bf16 bf16x8 __attribute__((ext_vector_type(8)));
typedef float f32x4 __attribute__((ext_vector_type(4)));
typedef unsigned short u16x4 __attribute__((ext_vector_type(4)));
typedef unsigned short u16x8 __attribute__((ext_vector_type(8)));

__device__ __forceinline__ u16 f2b(float f){
  __hip_bfloat16 h = __float2bfloat16(f);
  return *reinterpret_cast<u16*>(&h);
}
__device__ __forceinline__ float gelu_exact(float x){
  return 0.5f * x * (1.0f + erff(x * 0.70710678118654752f));
}
// tanh-form GELU (max |delta| vs exact ~1e-3; ~8 VALU ops vs ~25 for erff).
// Used only in k_token where erf sat on the GEMM2->GEMM-sm dependency chain.
__device__ __forceinline__ float gelu_fast(float x){
  const float z = 1.5957691216057308f * (x + 0.044715f * x * x * x);
  return x / (1.0f + __expf(-z));
}
// async global->LDS, 16B per lane; LDS dest = wave-uniform base + lane*16 (linear).
__device__ __forceinline__ void gload16(const void* g, void* l){
  __builtin_amdgcn_global_load_lds(
      (const __attribute__((address_space(1))) unsigned int*)g,
      (__attribute__((address_space(3))) unsigned int*)l, 16, 0, 0);
}

// ---------------- prep: layernorm + h = q@w1.T + b1  -> H bf16 [2048][128]
__global__ __launch_bounds__(256) void k_prep_h(
    const float* __restrict__ query, const float* __restrict__ ln_w,
    const float* __restrict__ ln_b, const float* __restrict__ w1,
    const float* __restrict__ b1, u16* __restrict__ H){
  const int t = blockIdx.x;
  const int tid = threadIdx.x;
  __shared__ float qs[CDIM];
  __shared__ float red[8];
  __shared__ float stat[2];
  float v = query[(size_t)t*CDIM + tid];
  float s = v, s2 = v*v;
  #pragma unroll
  for(int o=32;o>0;o>>=1){ s += __shfl_down(s,o,64); s2 += __shfl_down(s2,o,64); }
  const int wv = tid>>6;
  if((tid&63)==0){ red[wv]=s; red[4+wv]=s2; }
  __syncthreads();
  if(tid==0){
    float ss=red[0]+red[1]+red[2]+red[3];
    float qq=red[4]+red[5]+red[6]+red[7];
    float mu=ss/(float)CDIM;
    float var=qq/(float)CDIM - mu*mu;
    stat[0]=mu; stat[1]=rsqrtf(var+1e-6f);
  }
  __syncthreads();
  qs[tid] = (v - stat[0])*stat[1]*ln_w[tid] + ln_b[tid];
  __syncthreads();
  if(tid < HIDD){
    const float* wr = w1 + (size_t)tid*CDIM;
    float acc = b1[tid];
    #pragma unroll 8
    for(int c=0;c<CDIM;c++) acc += qs[c]*wr[c];
    H[(size_t)t*HIDD + tid] = f2b(acc);
  }
}

// ---------------- prep: w2 -> bf16 in FRAGMENT-BLOCKED layout (r13-verified).
__global__ __launch_bounds__(256) void k_prep_w2(
    const float* __restrict__ w2, const float* __restrict__ b2,
    u16* __restrict__ w2s, float* __restrict__ b2p){
  const int gid = blockIdx.x*256 + threadIdx.x;   // 66560*16 threads
  const int n  = gid >> 4;
  const int ch = gid & 15;
  if(n >= TOTSZ) return;
  int j;
  if(n < CCSZ){
    const int f = n >> 9, rem = n & 511;
    const int g = rem >> 7, r = (rem >> 3) & 15, e = rem & 7;
    const int d = (f >> 3)*16 + r;
    const int c = (f & 7)*32 + g*8 + e;
    j = c*256 + d;
  } else {
    j = n;
  }
  const float* src = w2 + (size_t)j*HIDD + ch*8;
  u16x8 tv;
  #pragma unroll
  for(int i=0;i<8;i++) tv[i] = f2b(src[i]);
  const int q = n >> 7, ks = ch >> 2, nt8 = (n >> 4) & 7, kg = ch & 3, r15 = n & 15;
  *(u16x8*)(w2s + ((size_t)((q*4 + ks)*8 + nt8))*512 + (kg*16 + r15)*8) = tv;
  if(ch == 0) b2p[n] = b2[j];
}

// ---------------- prep: proj_w -> bf16 in k'-PERMUTED order (r17-verified).
__global__ __launch_bounds__(256) void k_prep_pw(
    const float* __restrict__ pw, u16* __restrict__ pwb){
  const int gid = blockIdx.x*256 + threadIdx.x;   // 524288 u16x4 chunks (2048 blocks)
  const int e = gid >> 11;
  const int kp = (gid & 2047)*4;
  const int grp = kp >> 8;
  const int rem = kp & 255;
  const int g = rem >> 6, r15 = (rem >> 2) & 15;
  const int w_ = grp >> 2, mt = (grp >> 1) & 1, nt = grp & 1;
  const int o = nt*16 + r15;
  const int d0 = w_*32 + mt*16 + g*4;
  const float* s = pw + (size_t)e*8192 + o*256 + d0;
  u16x4 tv;
  tv[0]=f2b(s[0]); tv[1]=f2b(s[1]); tv[2]=f2b(s[2]); tv[3]=f2b(s[3]);
  *(u16x4*)(pwb + (size_t)e*8192 + kp) = tv;
}

// ---------------- params GEMM v9.3 = v9.2 with f-major pbuf copy-out (r20/r22 best).
// pbuf layout: [f][tok][512] (130 f-panels, f = n>>9). Block's n-tile q maps to
// f = q>>2, sub-range (q&3)*128. Copy-out: 4 tokens x 256B full lines at 1KB stride.
__global__ __launch_bounds__(256, 3) void k_params(
    const u16* __restrict__ H, const u16* __restrict__ w2s,
    const float* __restrict__ b2p, u16* __restrict__ pbuf, int chnk){
  __shared__ __align__(16) u16 S[4][16][136];
  const int tid = threadIdx.x;
  const int lane = tid & 63;
  const int w = tid >> 6;
  const int q = blockIdx.x;
  const int n0 = q * 128;
  const int r15 = lane & 15, g = lane >> 4;
  const int tb = blockIdx.y*128 + w*16;
  bf16x8 afr[2][4];
  #pragma unroll
  for(int m=0;m<2;m++){
    const u16* ap = H + (size_t)(tb + m*64 + r15)*HIDD + g*8;
    #pragma unroll
    for(int ks=0;ks<4;ks++) afr[m][ks] = *(const bf16x8*)(ap + ks*32);
  }
  float b2v[8];
  #pragma unroll
  for(int nt=0;nt<8;nt++) b2v[nt] = b2p[n0 + nt*16 + r15];
  f32x4 acc[2][8] = {};
  #pragma unroll
  for(int ks=0;ks<4;ks++){
    bf16x8 bfr[8];
    #pragma unroll
    for(int nt=0;nt<8;nt++)
      bfr[nt] = *(const bf16x8*)(w2s + ((size_t)((q*4 + ks)*8 + nt))*512 + lane*8);
    #pragma unroll
    for(int m=0;m<2;m++)
      #pragma unroll
      for(int nt=0;nt<8;nt++)
        acc[m][nt] = __builtin_amdgcn_mfma_f32_16x16x32_bf16(afr[m][ks], bfr[nt], acc[m][nt], 0,0,0);
  }
  #pragma unroll
  for(int m=0;m<2;m++){
    #pragma unroll
    for(int nt=0;nt<8;nt++)
      #pragma unroll
      for(int r=0;r<4;r++)
        S[w][g*4 + r][nt*16 + r15] = f2b(acc[m][nt][r] + b2v[nt]);
    // f-major copy-out: token row = 256B contiguous at (q&3)*128 within f-panel
    u16* dst = pbuf + ((size_t)(q>>2)*chnk + tb + m*64)*512 + (q&3)*128;
    #pragma unroll
    for(int i=0;i<4;i++){
      const int lt = i*4 + (lane >> 4);
      const int jc = lane & 15;
      *(u16x8*)(dst + (size_t)lt*512 + jc*8) = *(const u16x8*)&S[w][lt][jc*8];
    }
  }
}

// ---------------- per-token chain v9 = r20's v7 + fast gelu (r22 best).
__global__ __launch_bounds__(512, 2) void k_token(
    const float* __restrict__ xg, const u16* __restrict__ pbuf,
    const float* __restrict__ m_beta, const float* __restrict__ s_beta,
    u16* __restrict__ out2, int chnk){
  __shared__ u16 xs[PDIM][264];       // padded rows (r16-proven staging)
  __shared__ u16 o1[CDIM][36];        // per-wave rows
  const int tl = blockIdx.x;
  const int tid = threadIdx.x;
  const int lane = tid & 63;
  const int w = tid >> 6;             // 0..7, owns d-range [w*32, w*32+32)
  const int r15 = lane & 15, g = lane >> 4;

  // preload af fragments: 1KB contiguous per load
  bf16x8 af[2][8];
  #pragma unroll
  for(int ks=0;ks<8;ks++)
    #pragma unroll
    for(int mt=0;mt<2;mt++){
      const int f = (w*2+mt)*8 + ks;
      af[mt][ks] = *(const bf16x8*)(pbuf + ((size_t)f*chnk + tl)*512 + lane*8);
    }

  // stage xs -> bf16 LDS [p][c] (inline fp32 conversion — x read exactly once)
  {
    const f32x4* src = (const f32x4*)(xg + (size_t)tl*8192);
    #pragma unroll
    for(int i=0;i<4;i++){
      const int idx = tid + 512*i;
      f32x4 v = src[idx];
      const int flat = idx*4;
      const int p = flat >> 8, c = flat & 255;
      u16x4 t4; t4[0]=f2b(v[0]); t4[1]=f2b(v[1]); t4[2]=f2b(v[2]); t4[3]=f2b(v[3]);
      *(u16x4*)&xs[p][c] = t4;
    }
  }
  __syncthreads();

  // GEMM2: out1T[d][p] = sum_c cmT[d][c]*xs[p][c]
  f32x4 acc[2][2] = {};
  #pragma unroll
  for(int ks=0;ks<8;ks++){
    bf16x8 bf[2];
    #pragma unroll
    for(int nt=0;nt<2;nt++){
      const int p = nt*16 + r15;
      bf[nt] = *(const bf16x8*)&xs[p][ks*32 + g*8];
    }
    #pragma unroll
    for(int mt=0;mt<2;mt++)
      #pragma unroll
      for(int nt=0;nt<2;nt++)
        acc[mt][nt] = __builtin_amdgcn_mfma_f32_16x16x32_bf16(af[mt][ks], bf[nt], acc[mt][nt], 0,0,0);
  }
  // sm B-frags from f-major pbuf (panels 128..129): flat = o*32 + p
  bf16x8 bf2[2];
  #pragma unroll
  for(int nt=0;nt<2;nt++){
    const int o = nt*16 + r15;
    const int flat = o*32 + g*8;
    bf2[nt] = *(const bf16x8*)(pbuf + ((size_t)(128 + (flat>>9))*chnk + tl)*512 + (flat & 511));
  }
  // epilogue -> o1[d][p] (per-wave rows; NO barrier needed)
  #pragma unroll
  for(int mt=0;mt<2;mt++){
    const int d0 = w*32 + mt*16 + g*4;
    const f32x4 mb = *(const f32x4*)&m_beta[d0];
    #pragma unroll
    for(int nt=0;nt<2;nt++){
      const int p = nt*16 + r15;
      #pragma unroll
      for(int r=0;r<4;r++)
        o1[d0+r][p] = f2b(gelu_fast(acc[mt][nt][r] + mb[r]));
    }
  }
  // GEMM-sm: out2T[d][o] = sum_p o1[d][p]*sm[o][p] (same-wave o1 rows)
  f32x4 acc2[2][2] = {};
  {
    bf16x8 af2[2];
    #pragma unroll
    for(int mt=0;mt<2;mt++){
      const int d = w*32 + mt*16 + r15;
      af2[mt] = *(const bf16x8*)&o1[d][g*8];
    }
    #pragma unroll
    for(int mt=0;mt<2;mt++)
      #pragma unroll
      for(int nt=0;nt<2;nt++)
        acc2[mt][nt] = __builtin_amdgcn_mfma_f32_16x16x32_bf16(af2[mt], bf2[nt], acc2[mt][nt], 0,0,0);
  }
  // direct k'-layout stores: grp = w*4+mt*2+nt; addr = grp*256 + lane*4
  u16* dst = out2 + (size_t)tl*8192 + w*1024;
  #pragma unroll
  for(int nt=0;nt<2;nt++){
    const float sb = s_beta[nt*16 + r15];
    #pragma unroll
    for(int mt=0;mt<2;mt++){
      u16x4 t4;
      #pragma unroll
      for(int r=0;r<4;r++) t4[r] = f2b(gelu_fast(acc2[mt][nt][r] + sb));
      *(u16x4*)(dst + (mt*2+nt)*256 + lane*4) = t4;
    }
  }
}

// ---------------- proj GEMM: 2-phase LDS-pipelined (k'-space; r17-verified).
__global__ __launch_bounds__(512) void k_proj(
    const u16* __restrict__ out2, const u16* __restrict__ pwb,
    float* __restrict__ part){
  __shared__ u16 Ab[2][64*32];
  __shared__ u16 Bb[2][256*32];
  const int tid = threadIdx.x;
  const int lane = tid & 63, w = tid >> 6;
  const int r15 = lane & 15, g = lane >> 4;
  const int m0 = blockIdx.x * 64;
  const int k0 = blockIdx.y * 512;
  const int wm = (w >> 2) * 32;
  const int wn = (w & 3) * 64;
  const int srow = lane >> 2;
  const int cs   = lane & 3;
  const int a_row = (w & 3)*16 + srow;
  const u16* a_src = out2 + (size_t)(m0 + a_row)*8192 + k0 + (size_t)((cs ^ (a_row & 3))*8);
  const int b_row0 = (2*w)*16 + srow;
  const int b_row1 = (2*w+1)*16 + srow;
  const u16* b_src0 = pwb + (size_t)b_row0*8192 + k0 + (size_t)((cs ^ (b_row0 & 3))*8);
  const u16* b_src1 = pwb + (size_t)b_row1*8192 + k0 + (size_t)((cs ^ (b_row1 & 3))*8);

  f32x4 acc[2][4] = {};

  #define STAGE(buf, kt) do{                                         \
    const int ko = (kt)*32;                                          \
    if(w < 4) gload16(a_src + ko, (char*)&Ab[buf][0] + w*1024);      \
    gload16(b_src0 + ko, (char*)&Bb[buf][0] + (2*w)*1024);           \
    gload16(b_src1 + ko, (char*)&Bb[buf][0] + (2*w+1)*1024);         \
  }while(0)

  STAGE(0, 0);
  __syncthreads();
  int cur = 0;
  for(int kt=0; kt<16; kt++){
    if(kt < 15){ STAGE(cur^1, kt+1); }
    bf16x8 af[2], bf[4];
    #pragma unroll
    for(int mt=0;mt<2;mt++){
      const int row = wm + mt*16 + r15;
      af[mt] = *(const bf16x8*)((char*)&Ab[cur][0] + row*64 + ((g ^ (row&3))*16));
    }
    #pragma unroll
    for(int nt=0;nt<4;nt++){
      const int row = wn + nt*16 + r15;
      bf[nt] = *(const bf16x8*)((char*)&Bb[cur][0] + row*64 + ((g ^ (row&3))*16));
    }
    #pragma unroll
    for(int mt=0;mt<2;mt++)
      #pragma unroll
      for(int nt=0;nt<4;nt++)
        acc[mt][nt] = __builtin_amdgcn_mfma_f32_16x16x32_bf16(af[mt], bf[nt], acc[mt][nt], 0,0,0);
    __syncthreads();
    cur ^= 1;
  }
  #undef STAGE

  float* pbase = part + (size_t)blockIdx.y*TKN*CDIM;
  #pragma unroll
  for(int mt=0;mt<2;mt++)
    #pragma unroll
    for(int nt=0;nt<4;nt++){
      const int t = m0 + wm + mt*16 + g*4;
      const int e = wn + nt*16 + r15;
      #pragma unroll
      for(int r=0;r<4;r++)
        pbase[(size_t)(t+r)*CDIM + e] = acc[mt][nt][r];
    }
}

// ---------------- combine partials + proj_b (f32x4 vectorized; 512 blocks)
__global__ __launch_bounds__(256) void k_combine(
    const float* __restrict__ part, const float* __restrict__ pb,
    float* __restrict__ out){
  const int i4 = blockIdx.x*256 + threadIdx.x;   // 131072 f32x4's
  const int e4 = (i4 & 63)*4;
  f32x4 s = *(const f32x4*)&pb[e4];
  #pragma unroll
  for(int z=0;z<KSPL;z++) s += *(const f32x4*)&part[(size_t)z*524288 + (size_t)i4*4];
  *(f32x4*)&out[(size_t)i4*4] = s;
}

extern "C" void kernel_launch(void* const* d_in, const int* in_sizes, int n_in,
                              void* d_out, int out_size, void* d_ws, size_t ws_size,
                              hipStream_t stream){
  const float* x     = (const float*)d_in[0];
  const float* query = (const float*)d_in[1];
  const float* ln_w  = (const float*)d_in[2];
  const float* ln_b  = (const float*)d_in[3];
  const float* w1    = (const float*)d_in[4];
  const float* b1    = (const float*)d_in[5];
  const float* w2    = (const float*)d_in[6];
  const float* b2    = (const float*)d_in[7];
  const float* m_beta= (const float*)d_in[8];
  const float* s_beta= (const float*)d_in[9];
  const float* pw    = (const float*)d_in[10];
  const float* pb    = (const float*)d_in[11];
  float* out = (float*)d_out;
  char* ws = (char*)d_ws;

  // chnk=1024 (r13/r16/r20/r22 best). Needs ~192 MB (measured ws = 256 MiB).
  const size_t need_big = 192u*1024u*1024u;
  const int chnk = (ws_size >= need_big) ? 1024 : 256;
  const int nch  = TKN / chnk;

  size_t off = 0;
  u16* H     = (u16*)(ws + off);  off += (size_t)TKN*HIDD*2;        // 0.5 MB
  u16* w2s   = (u16*)(ws + off);  off += (size_t)TOTSZ*HIDD*2;      // 17 MB
  float* b2p = (float*)(ws + off);off += (size_t)TOTSZ*4;           // 0.27 MB
  u16* pwb   = (u16*)(ws + off);  off += (size_t)CDIM*8192*2;       // 4 MB
  u16* pbuf  = (u16*)(ws + off);  off += (size_t)chnk*TOTSZ*2;      // 136 MB (130 f-panels)
  u16* out2  = (u16*)(ws + off);  off += (size_t)TKN*8192*2;        // 33.5 MB
  // part (16 x 2048 x 256 fp32 = 33.55 MB) aliases pbuf (>=34 MB, dead by k_proj).
  float* part= (float*)pbuf;

  k_prep_h<<<TKN, 256, 0, stream>>>(query, ln_w, ln_b, w1, b1, H);
  k_prep_w2<<<4160, 256, 0, stream>>>(w2, b2, w2s, b2p);
  k_prep_pw<<<2048, 256, 0, stream>>>(pw, pwb);
  for(int ch=0; ch<nch; ch++){
    k_params<<<dim3(520, chnk/128), 256, 0, stream>>>(H + (size_t)ch*chnk*HIDD, w2s, b2p, pbuf, chnk);
    k_token<<<chnk, 512, 0, stream>>>(x + (size_t)ch*chnk*8192, pbuf, m_beta, s_beta,
                                      out2 + (size_t)ch*chnk*8192, chnk);
  }
  k_proj<<<dim3(32,KSPL), 512, 0, stream>>>(out2, pwb, part);
  k_combine<<<512, 256, 0, stream>>>(part, pb, out);
}